// Round 4
// baseline (4337.771 us; speedup 1.0000x reference)
//
#include <hip/hip_runtime.h>
#include <math.h>

#define TOKENS 16384
#define DIM    7168
#define NEXP   256
#define TK     8
#define BM     32
#define BK     32
#define NKT    (DIM / BK)   /* 224 */
#define DELTA  8.0e-3f      /* candidate margin on f32 logits */

// LDS float layout (strides ≡5 mod 32 → stash writes ≤2-way conflicts):
//   As[2][32][37], Bs[2][32][261]; epilogue overlay lgf[32][260] f32.
#define AS_OFF(buf)  ((buf) * (32 * 37))
#define BS_OFF(buf)  (2 * 32 * 37 + (buf) * (32 * 261))
#define LDS_FLOATS   (2 * 32 * 37 + 2 * 32 * 261)
#define LDS_BYTES    (LDS_FLOATS * 4)   /* 76288 B -> 2 blocks/CU */

__global__ __launch_bounds__(256, 2)
void gate_f32r(const float* __restrict__ x,
               const float* __restrict__ w,
               float* __restrict__ outw,
               float* __restrict__ outi)
{
    extern __shared__ __align__(16) float smemf[];
    float* lgf = smemf;   // epilogue overlay [32][260]

    const int t    = threadIdx.x;
    const int tx   = t & 31;     // expert coord: experts tx*4+{0..3}, +128
    const int ty   = t >> 5;     // token coord:  tokens  ty*4+{0..3}
    const int lane = t & 63;
    const int wv   = t >> 6;
    const int tok0 = blockIdx.x * BM;

    const int ldq = t >> 3;          // 0..31
    const int kq  = (t & 7) * 4;     // 0,4,...,28

    const float* xp = x + (size_t)(tok0 + ldq) * DIM + kq;
    const float* wp = w + (size_t)ldq * DIM + kq;

    float acc[2][4][4];
    #pragma unroll
    for (int eg = 0; eg < 2; ++eg)
        #pragma unroll
        for (int i = 0; i < 4; ++i)
            #pragma unroll
            for (int j = 0; j < 4; ++j)
                acc[eg][i][j] = 0.0f;

    float4 ar, br0, br1, br2, br3, br4, br5, br6, br7;

#define LOADT(kt) do {                                        \
    const float* xq = xp + (size_t)(kt) * BK;                 \
    ar  = *(const float4*)(xq);                               \
    const float* wq = wp + (size_t)(kt) * BK;                 \
    br0 = *(const float4*)(wq);                               \
    br1 = *(const float4*)(wq + (size_t) 32 * DIM);           \
    br2 = *(const float4*)(wq + (size_t) 64 * DIM);           \
    br3 = *(const float4*)(wq + (size_t) 96 * DIM);           \
    br4 = *(const float4*)(wq + (size_t)128 * DIM);           \
    br5 = *(const float4*)(wq + (size_t)160 * DIM);           \
    br6 = *(const float4*)(wq + (size_t)192 * DIM);           \
    br7 = *(const float4*)(wq + (size_t)224 * DIM);           \
} while (0)

#define STB(Bw, i, v)                                         \
    (Bw)[(kq+0)*261 + ldq + (i)*32] = (v).x;                  \
    (Bw)[(kq+1)*261 + ldq + (i)*32] = (v).y;                  \
    (Bw)[(kq+2)*261 + ldq + (i)*32] = (v).z;                  \
    (Bw)[(kq+3)*261 + ldq + (i)*32] = (v).w;

#define STASH(buf) do {                                       \
    float* Aw = smemf + AS_OFF(buf);                          \
    Aw[(kq+0)*37 + ldq] = ar.x;                               \
    Aw[(kq+1)*37 + ldq] = ar.y;                               \
    Aw[(kq+2)*37 + ldq] = ar.z;                               \
    Aw[(kq+3)*37 + ldq] = ar.w;                               \
    float* Bw = smemf + BS_OFF(buf);                          \
    STB(Bw, 0, br0) STB(Bw, 1, br1) STB(Bw, 2, br2)           \
    STB(Bw, 3, br3) STB(Bw, 4, br4) STB(Bw, 5, br5)           \
    STB(Bw, 6, br6) STB(Bw, 7, br7)                           \
} while (0)

    LOADT(0);
    STASH(0);
    __syncthreads();

    for (int kt = 0; kt < NKT; ++kt) {
        const int cur = kt & 1;
        if (kt + 1 < NKT) LOADT(kt + 1);
        const float* Ac = smemf + AS_OFF(cur);
        const float* Bc = smemf + BS_OFF(cur);
        #pragma unroll 16
        for (int kk = 0; kk < BK; ++kk) {
            float4 a4 = *(const float4*)(Ac + kk * 37 + ty * 4);
            float4 b0 = *(const float4*)(Bc + kk * 261 + tx * 4);
            float4 b1 = *(const float4*)(Bc + kk * 261 + tx * 4 + 128);
            float af[4], b0f[4], b1f[4];
            af[0]=a4.x; af[1]=a4.y; af[2]=a4.z; af[3]=a4.w;
            b0f[0]=b0.x; b0f[1]=b0.y; b0f[2]=b0.z; b0f[3]=b0.w;
            b1f[0]=b1.x; b1f[1]=b1.y; b1f[2]=b1.z; b1f[3]=b1.w;
            #pragma unroll
            for (int i = 0; i < 4; ++i)
                #pragma unroll
                for (int j = 0; j < 4; ++j) {
                    acc[0][i][j] = fmaf(af[i], b0f[j], acc[0][i][j]);
                    acc[1][i][j] = fmaf(af[i], b1f[j], acc[1][i][j]);
                }
        }
        if (kt + 1 < NKT) STASH((kt + 1) & 1);
        __syncthreads();
    }

    // ---- E1: f32 logits to LDS overlay (stride 260) ----
    #pragma unroll
    for (int i = 0; i < 4; ++i) {
        float* lr = lgf + (size_t)(ty * 4 + i) * 260 + tx * 4;
        float4 v0, v1;
        v0.x = acc[0][i][0]; v0.y = acc[0][i][1];
        v0.z = acc[0][i][2]; v0.w = acc[0][i][3];
        v1.x = acc[1][i][0]; v1.y = acc[1][i][1];
        v1.z = acc[1][i][2]; v1.w = acc[1][i][3];
        *(float4*)(lr)       = v0;
        *(float4*)(lr + 128) = v1;
    }
    __syncthreads();

    // ---- E2: softmax + candidate top-k + f64 repair; wave owns 8 tokens ----
    for (int r8 = 0; r8 < 8; ++r8) {
        const int row  = wv * 8 + r8;
        const int gtok = tok0 + row;
        float4 v = *(const float4*)(lgf + (size_t)row * 260 + lane * 4);
        float vv[4] = {v.x, v.y, v.z, v.w};

        float m = fmaxf(fmaxf(vv[0], vv[1]), fmaxf(vv[2], vv[3]));
        #pragma unroll
        for (int off = 32; off >= 1; off >>= 1)
            m = fmaxf(m, __shfl_xor(m, off));

        float s = expf(vv[0] - m) + expf(vv[1] - m)
                + expf(vv[2] - m) + expf(vv[3] - m);
        #pragma unroll
        for (int off = 32; off >= 1; off >>= 1)
            s += __shfl_xor(s, off);
        const float invs = 1.0f / s;

        // provisional extraction: top-8 plus near-ties within DELTA (cap 16)
        int   taken = 0;
        int   ncand = 0;
        float s8    = 0.0f;
        float my_cv = -INFINITY;   // (unused value, kept for clarity)
        int   my_ci = 1 << 30;
        for (int it = 0; it < 16; ++it) {
            float bv = -INFINITY;
            int   bi = 1 << 30;
            #pragma unroll
            for (int j = 0; j < 4; ++j) {
                float cv = ((taken >> j) & 1) ? -INFINITY : vv[j];
                int   ci = lane * 4 + j;
                if (cv > bv || (cv == bv && ci < bi)) { bv = cv; bi = ci; }
            }
            #pragma unroll
            for (int off = 32; off >= 1; off >>= 1) {
                float ov = __shfl_xor(bv, off);
                int   oi = __shfl_xor(bi, off);
                if (ov > bv || (ov == bv && oi < bi)) { bv = ov; bi = oi; }
            }
            if (it == 7) s8 = bv;
            if (it >= 8 && bv < s8 - DELTA) break;   // uniform: bv,s8 uniform
            if (lane == it) { my_cv = bv; my_ci = bi; }
            if ((bi >> 2) == lane) taken |= 1 << (bi & 3);
            ncand = it + 1;
        }
        (void)my_cv;

        // f64 repair: exact dot for each candidate expert (wave-parallel K)
        double ev = -1.0e300;
        const float* xrow = x + (size_t)gtok * DIM;
        for (int c = 0; c < ncand; ++c) {
            const int e = __shfl(my_ci, c);
            const float* wrow = w + (size_t)e * DIM;
            double a2 = 0.0;
            #pragma unroll 4
            for (int j = 0; j < 28; ++j) {
                float4 xa = *(const float4*)(xrow + j * 256 + lane * 4);
                float4 wa = *(const float4*)(wrow + j * 256 + lane * 4);
                a2 = fma((double)xa.x, (double)wa.x, a2);
                a2 = fma((double)xa.y, (double)wa.y, a2);
                a2 = fma((double)xa.z, (double)wa.z, a2);
                a2 = fma((double)xa.w, (double)wa.w, a2);
            }
            #pragma unroll
            for (int off = 32; off >= 1; off >>= 1)
                a2 += __shfl_xor(a2, off);
            if (lane == c) ev = a2;
        }

        // final exact top-8 among candidate lanes
        for (int it = 0; it < TK; ++it) {
            double bv2 = ev;
            int    bi2 = my_ci;
            int    bs2 = lane;
            #pragma unroll
            for (int off = 32; off >= 1; off >>= 1) {
                double ov = __shfl_xor(bv2, off);
                int    oi = __shfl_xor(bi2, off);
                int    os = __shfl_xor(bs2, off);
                if (ov > bv2 || (ov == bv2 && oi < bi2)) {
                    bv2 = ov; bi2 = oi; bs2 = os;
                }
            }
            if (lane == it) {
                outw[(size_t)gtok * TK + it] = expf((float)bv2 - m) * invs;
                outi[(size_t)gtok * TK + it] = (float)bi2;
            }
            if (lane == bs2) ev = -1.0e300;   // remove winner
        }
    }
}

extern "C" void kernel_launch(void* const* d_in, const int* in_sizes, int n_in,
                              void* d_out, int out_size, void* d_ws, size_t ws_size,
                              hipStream_t stream) {
    const float* x = (const float*)d_in[0];
    const float* w = (const float*)d_in[1];
    float* outw = (float*)d_out;
    float* outi = outw + (size_t)TOKENS * TK;
    gate_f32r<<<dim3(TOKENS / BM), dim3(256), LDS_BYTES, stream>>>(x, w, outw, outi);
}

// Round 5
// 4021.352 us; speedup vs baseline: 1.0787x; 1.0787x over previous
//
#include <hip/hip_runtime.h>
#include <math.h>

#define TOKENS 16384
#define DIM    7168
#define NEXP   256
#define TK     8
#define BM     32
#define BK     32
#define NKT    (DIM / BK)   /* 224 */
#define DELTA  8.0e-3f      /* candidate margin on f32 logits */
#define MAXC   12

// LDS float layout (strides ≡5 mod 32 → stash writes ≤2-way conflicts):
//   As[2][32][37], Bs[2][32][261]; epilogue overlay lgf[32][260] f32.
#define AS_OFF(buf)  ((buf) * (32 * 37))
#define BS_OFF(buf)  (2 * 32 * 37 + (buf) * (32 * 261))
#define LDS_FLOATS   (2 * 32 * 37 + 2 * 32 * 261)
#define LDS_BYTES    (LDS_FLOATS * 4)   /* 76288 B -> 2 blocks/CU */

__global__ __launch_bounds__(256, 2)
void gate_f32r(const float* __restrict__ x,
               const float* __restrict__ w,
               float* __restrict__ outw,
               float* __restrict__ outi)
{
    extern __shared__ __align__(16) float smemf[];
    float* lgf = smemf;   // epilogue overlay [32][260]

    const int t    = threadIdx.x;
    const int tx   = t & 31;
    const int ty   = t >> 5;
    const int lane = t & 63;
    const int wv   = t >> 6;
    const int tok0 = blockIdx.x * BM;

    const int ldq = t >> 3;
    const int kq  = (t & 7) * 4;

    const float* xp = x + (size_t)(tok0 + ldq) * DIM + kq;
    const float* wp = w + (size_t)ldq * DIM + kq;

    float acc[2][4][4];
    #pragma unroll
    for (int eg = 0; eg < 2; ++eg)
        #pragma unroll
        for (int i = 0; i < 4; ++i)
            #pragma unroll
            for (int j = 0; j < 4; ++j)
                acc[eg][i][j] = 0.0f;

    float4 ar, br0, br1, br2, br3, br4, br5, br6, br7;

#define LOADT(kt) do {                                        \
    const float* xq = xp + (size_t)(kt) * BK;                 \
    ar  = *(const float4*)(xq);                               \
    const float* wq = wp + (size_t)(kt) * BK;                 \
    br0 = *(const float4*)(wq);                               \
    br1 = *(const float4*)(wq + (size_t) 32 * DIM);           \
    br2 = *(const float4*)(wq + (size_t) 64 * DIM);           \
    br3 = *(const float4*)(wq + (size_t) 96 * DIM);           \
    br4 = *(const float4*)(wq + (size_t)128 * DIM);           \
    br5 = *(const float4*)(wq + (size_t)160 * DIM);           \
    br6 = *(const float4*)(wq + (size_t)192 * DIM);           \
    br7 = *(const float4*)(wq + (size_t)224 * DIM);           \
} while (0)

#define STB(Bw, i, v)                                         \
    (Bw)[(kq+0)*261 + ldq + (i)*32] = (v).x;                  \
    (Bw)[(kq+1)*261 + ldq + (i)*32] = (v).y;                  \
    (Bw)[(kq+2)*261 + ldq + (i)*32] = (v).z;                  \
    (Bw)[(kq+3)*261 + ldq + (i)*32] = (v).w;

#define STASH(buf) do {                                       \
    float* Aw = smemf + AS_OFF(buf);                          \
    Aw[(kq+0)*37 + ldq] = ar.x;                               \
    Aw[(kq+1)*37 + ldq] = ar.y;                               \
    Aw[(kq+2)*37 + ldq] = ar.z;                               \
    Aw[(kq+3)*37 + ldq] = ar.w;                               \
    float* Bw = smemf + BS_OFF(buf);                          \
    STB(Bw, 0, br0) STB(Bw, 1, br1) STB(Bw, 2, br2)           \
    STB(Bw, 3, br3) STB(Bw, 4, br4) STB(Bw, 5, br5)           \
    STB(Bw, 6, br6) STB(Bw, 7, br7)                           \
} while (0)

    LOADT(0);
    STASH(0);
    __syncthreads();

    for (int kt = 0; kt < NKT; ++kt) {
        const int cur = kt & 1;
        if (kt + 1 < NKT) LOADT(kt + 1);
        const float* Ac = smemf + AS_OFF(cur);
        const float* Bc = smemf + BS_OFF(cur);
        #pragma unroll 16
        for (int kk = 0; kk < BK; ++kk) {
            float4 a4 = *(const float4*)(Ac + kk * 37 + ty * 4);
            float4 b0 = *(const float4*)(Bc + kk * 261 + tx * 4);
            float4 b1 = *(const float4*)(Bc + kk * 261 + tx * 4 + 128);
            float af[4], b0f[4], b1f[4];
            af[0]=a4.x; af[1]=a4.y; af[2]=a4.z; af[3]=a4.w;
            b0f[0]=b0.x; b0f[1]=b0.y; b0f[2]=b0.z; b0f[3]=b0.w;
            b1f[0]=b1.x; b1f[1]=b1.y; b1f[2]=b1.z; b1f[3]=b1.w;
            #pragma unroll
            for (int i = 0; i < 4; ++i)
                #pragma unroll
                for (int j = 0; j < 4; ++j) {
                    acc[0][i][j] = fmaf(af[i], b0f[j], acc[0][i][j]);
                    acc[1][i][j] = fmaf(af[i], b1f[j], acc[1][i][j]);
                }
        }
        if (kt + 1 < NKT) STASH((kt + 1) & 1);
        __syncthreads();
    }

    // ---- E1: f32 logits to LDS overlay (stride 260) ----
    #pragma unroll
    for (int i = 0; i < 4; ++i) {
        float* lr = lgf + (size_t)(ty * 4 + i) * 260 + tx * 4;
        float4 v0, v1;
        v0.x = acc[0][i][0]; v0.y = acc[0][i][1];
        v0.z = acc[0][i][2]; v0.w = acc[0][i][3];
        v1.x = acc[1][i][0]; v1.y = acc[1][i][1];
        v1.z = acc[1][i][2]; v1.w = acc[1][i][3];
        *(float4*)(lr)       = v0;
        *(float4*)(lr + 128) = v1;
    }
    __syncthreads();

    // ---- E2: softmax + candidates + grouped f64 repair; wave owns 8 tokens ----
    for (int r8 = 0; r8 < 8; ++r8) {
        const int row  = wv * 8 + r8;
        const int gtok = tok0 + row;
        float4 v = *(const float4*)(lgf + (size_t)row * 260 + lane * 4);
        float vv[4] = {v.x, v.y, v.z, v.w};

        float m = fmaxf(fmaxf(vv[0], vv[1]), fmaxf(vv[2], vv[3]));
        #pragma unroll
        for (int off = 32; off >= 1; off >>= 1)
            m = fmaxf(m, __shfl_xor(m, off));

        float s = expf(vv[0] - m) + expf(vv[1] - m)
                + expf(vv[2] - m) + expf(vv[3] - m);
        #pragma unroll
        for (int off = 32; off >= 1; off >>= 1)
            s += __shfl_xor(s, off);
        const float invs = 1.0f / s;

        // provisional extraction: top-8 plus near-ties within DELTA (cap MAXC)
        int   taken = 0;
        int   ncand = 0;
        float s8    = 0.0f;
        int   my_ci = 1 << 30;
        for (int it = 0; it < MAXC; ++it) {
            float bv = -INFINITY;
            int   bi = 1 << 30;
            #pragma unroll
            for (int j = 0; j < 4; ++j) {
                float cv = ((taken >> j) & 1) ? -INFINITY : vv[j];
                int   ci = lane * 4 + j;
                if (cv > bv || (cv == bv && ci < bi)) { bv = cv; bi = ci; }
            }
            #pragma unroll
            for (int off = 32; off >= 1; off >>= 1) {
                float ov = __shfl_xor(bv, off);
                int   oi = __shfl_xor(bi, off);
                if (ov > bv || (ov == bv && oi < bi)) { bv = ov; bi = oi; }
            }
            if (it == 7) s8 = bv;
            if (it >= 8 && bv < s8 - DELTA) break;   // wave-uniform
            if (lane == it) my_ci = bi;
            if ((bi >> 2) == lane) taken |= 1 << (bi & 3);
            ncand = it + 1;
        }

        // grouped f64 repair: 4 candidates per x pass, x chunk reused
        const float* xrow = x + (size_t)gtok * DIM + lane * 4;
        double ev = -1.0e300;

#define RGROUP(base) do {                                                     \
    const int i0 = ((base)+0 < ncand) ? (base)+0 : ncand-1;                   \
    const int i1 = ((base)+1 < ncand) ? (base)+1 : ncand-1;                   \
    const int i2 = ((base)+2 < ncand) ? (base)+2 : ncand-1;                   \
    const int i3 = ((base)+3 < ncand) ? (base)+3 : ncand-1;                   \
    const float* wA = w + (size_t)__shfl(my_ci, i0) * DIM + lane * 4;         \
    const float* wB = w + (size_t)__shfl(my_ci, i1) * DIM + lane * 4;         \
    const float* wC = w + (size_t)__shfl(my_ci, i2) * DIM + lane * 4;         \
    const float* wD = w + (size_t)__shfl(my_ci, i3) * DIM + lane * 4;         \
    double aA = 0.0, aB = 0.0, aC = 0.0, aD = 0.0;                            \
    _Pragma("unroll 2")                                                       \
    for (int j = 0; j < 28; ++j) {                                            \
        float4 xa = *(const float4*)(xrow + j * 256);                         \
        float4 qa = *(const float4*)(wA + j * 256);                           \
        float4 qb = *(const float4*)(wB + j * 256);                           \
        float4 qc = *(const float4*)(wC + j * 256);                           \
        float4 qd = *(const float4*)(wD + j * 256);                           \
        aA = fma((double)xa.x, (double)qa.x, aA);                             \
        aA = fma((double)xa.y, (double)qa.y, aA);                             \
        aA = fma((double)xa.z, (double)qa.z, aA);                             \
        aA = fma((double)xa.w, (double)qa.w, aA);                             \
        aB = fma((double)xa.x, (double)qb.x, aB);                             \
        aB = fma((double)xa.y, (double)qb.y, aB);                             \
        aB = fma((double)xa.z, (double)qb.z, aB);                             \
        aB = fma((double)xa.w, (double)qb.w, aB);                             \
        aC = fma((double)xa.x, (double)qc.x, aC);                             \
        aC = fma((double)xa.y, (double)qc.y, aC);                             \
        aC = fma((double)xa.z, (double)qc.z, aC);                             \
        aC = fma((double)xa.w, (double)qc.w, aC);                             \
        aD = fma((double)xa.x, (double)qd.x, aD);                             \
        aD = fma((double)xa.y, (double)qd.y, aD);                             \
        aD = fma((double)xa.z, (double)qd.z, aD);                             \
        aD = fma((double)xa.w, (double)qd.w, aD);                             \
    }                                                                         \
    _Pragma("unroll")                                                         \
    for (int off = 32; off >= 1; off >>= 1) {                                 \
        aA += __shfl_xor(aA, off);                                            \
        aB += __shfl_xor(aB, off);                                            \
        aC += __shfl_xor(aC, off);                                            \
        aD += __shfl_xor(aD, off);                                            \
    }                                                                         \
    double gv = (lane == (base)+0) ? aA : (lane == (base)+1) ? aB :           \
                (lane == (base)+2) ? aC : aD;                                 \
    if (lane >= (base) && lane < (base)+4 && lane < ncand) ev = gv;           \
} while (0)

        RGROUP(0);
        RGROUP(4);
        if (ncand > 8) RGROUP(8);

        // final exact top-8 among candidate lanes
        for (int it = 0; it < TK; ++it) {
            double bv2 = ev;
            int    bi2 = my_ci;
            int    bs2 = lane;
            #pragma unroll
            for (int off = 32; off >= 1; off >>= 1) {
                double ov = __shfl_xor(bv2, off);
                int    oi = __shfl_xor(bi2, off);
                int    os = __shfl_xor(bs2, off);
                if (ov > bv2 || (ov == bv2 && oi < bi2)) {
                    bv2 = ov; bi2 = oi; bs2 = os;
                }
            }
            if (lane == it) {
                outw[(size_t)gtok * TK + it] = expf((float)bv2 - m) * invs;
                outi[(size_t)gtok * TK + it] = (float)bi2;
            }
            if (lane == bs2) ev = -1.0e300;
        }
    }
}

extern "C" void kernel_launch(void* const* d_in, const int* in_sizes, int n_in,
                              void* d_out, int out_size, void* d_ws, size_t ws_size,
                              hipStream_t stream) {
    const float* x = (const float*)d_in[0];
    const float* w = (const float*)d_in[1];
    float* outw = (float*)d_out;
    float* outi = outw + (size_t)TOKENS * TK;
    gate_f32r<<<dim3(TOKENS / BM), dim3(256), LDS_BYTES, stream>>>(x, w, outw, outi);
}